// Round 11
// baseline (161.329 us; speedup 1.0000x reference)
//
#include <hip/hip_runtime.h>
#include <stdint.h>

// DenseAttention_61598420959334 — round 11:
//   k_gram rebuilt wave-independent: each wave processes 4 private 32-row
//   tiles (load -> cvt_pk bf16 -> private-LDS tr-layout -> lgkm wait ->
//   tr-read 8 frags -> 36 triangle MFMAs), NO barriers in the hot loop.
//   Single bf16 plane (scores robust: gaps ~100s vs error ~0.3).
//   G symmetric: upper triangle only, mirrored in the end-of-kernel
//   4-phase LDS reduction (only once-per-kernel barriers).
//   k_reduce / k_mid / k_out16 / k_out32 = r10 versions (passing).

#define DD 128
#define ROWS_PER_BLK 512
#define PART_STRIDE 16512  // 16384 G-partial + 128 s-partial

// tr-read LDS tile layout (r8/r10 hardware-verified):
//   element (j, d): short off = 648*(d>>4) + 320*((j>>2)&1) + 64*(j>>3)
//                               + 16*(j&3) + (d&15)
//   frag a (byte addr): wavebase + a*1296 + r*640 + 8*l   (r = 0,1)
#define TILE_SH 5184   // shorts per wave tile
#define TILE_B  10368  // bytes per wave tile

typedef float f32x4 __attribute__((ext_vector_type(4)));
typedef short s16x8 __attribute__((ext_vector_type(8)));
typedef float fvec4 __attribute__((ext_vector_type(4)));

__device__ __forceinline__ unsigned short f2bf(float f) {
    union { float f; uint32_t u; } v; v.f = f;
    uint32_t u = v.u;
    u += 0x7FFFu + ((u >> 16) & 1u);
    return (unsigned short)(u >> 16);
}
__device__ __forceinline__ s16x8 mk8(uint64_t lo, uint64_t hi) {
    union { uint64_t u[2]; s16x8 v; } x; x.u[0] = lo; x.u[1] = hi; return x.v;
}

// ---------------------------------------------------------------- pass 1: Gram
__global__ __launch_bounds__(256) void k_gram(const float* __restrict__ x,
                                              float* __restrict__ ws,
                                              unsigned short* __restrict__ x16) {
    __shared__ __align__(16) unsigned char smem[66048];
    short* tiles = (short*)smem;                 // wave w at w*TILE_SH (aliased)
    float* grid  = (float*)smem;                 // 16384 f, used after tiles
    float* sgrid = (float*)(smem + 65536);       // 128 f

    const int t = threadIdx.x;
    const int l = t & 63, w = t >> 6;
    const long rowbase = (long)blockIdx.x * ROWS_PER_BLK + (long)w * 128;
    const fvec4* xg = (const fvec4*)x;
    short* myt = tiles + w * TILE_SH;
    const unsigned mybase = (unsigned)(uintptr_t)myt;

    f32x4 acc[36] = {};          // upper triangle (a<=b), compile-time indexed
    float sacc0 = 0.f, sacc1 = 0.f, sacc2 = 0.f, sacc3 = 0.f;

    const int jrow = l >> 5;     // 0/1: which of the 2 rows per iteration
    const int cq   = l & 31;     // column quad index (d0 = 4*cq)

#pragma unroll 1
    for (int tl = 0; tl < 4; ++tl) {
        long r0 = rowbase + tl * 32;

        // ---- load 32x128 f32 tile, column-stationary (coalesced 512B rows)
        fvec4 va[8], vb[8];
#pragma unroll
        for (int i = 0; i < 8; ++i) {
            long row = r0 + 2 * i + jrow;
            va[i] = xg[row * 32 + cq];
        }
#pragma unroll
        for (int i = 0; i < 8; ++i) {
            long row = r0 + 2 * (i + 8) + jrow;
            vb[i] = xg[row * 32 + cq];
        }

        // ---- cvt to bf16, write private LDS tr-layout, dump x16, s-partials
#pragma unroll
        for (int i = 0; i < 16; ++i) {
            fvec4 v = (i < 8) ? va[i & 7] : vb[i & 7];
            int j = 2 * i + jrow;
            int d0 = 4 * cq;
            uint32_t h0, h1;
            asm("v_cvt_pk_bf16_f32 %0, %1, %2" : "=v"(h0) : "v"(v[0]), "v"(v[1]));
            asm("v_cvt_pk_bf16_f32 %0, %1, %2" : "=v"(h1) : "v"(v[2]), "v"(v[3]));
            uint64_t ph = (uint64_t)h0 | ((uint64_t)h1 << 32);
            int off = 648 * (d0 >> 4) + 320 * ((j >> 2) & 1) + 64 * (j >> 3) +
                      16 * (j & 3) + (d0 & 15);
            *(uint64_t*)&myt[off] = ph;
            if (x16)
                *(uint64_t*)&x16[(r0 + j) * 128 + d0] = ph;
            sacc0 += v[0]; sacc1 += v[1]; sacc2 += v[2]; sacc3 += v[3];
        }

        // ---- within-wave LDS drain (no cross-wave dependency -> no barrier)
        asm volatile("s_waitcnt lgkmcnt(0)" ::: "memory");
        __builtin_amdgcn_sched_barrier(0);

        // ---- tr-read the 8 x^T fragments
        uint64_t fr[8][2];
#pragma unroll
        for (int a = 0; a < 8; ++a)
#pragma unroll
            for (int r = 0; r < 2; ++r) {
                unsigned ad = mybase + (unsigned)(a * 1296 + r * 640) + 8u * (unsigned)l;
                asm volatile("ds_read_b64_tr_b16 %0, %1"
                             : "=v"(fr[a][r]) : "v"(ad));
            }
        asm volatile("s_waitcnt lgkmcnt(0)" ::: "memory");
        __builtin_amdgcn_sched_barrier(0);

        s16x8 fg[8];
#pragma unroll
        for (int a = 0; a < 8; ++a) fg[a] = mk8(fr[a][0], fr[a][1]);

        // ---- 36 independent triangle MFMAs (no RAW chains within a tile)
        {
            int idx = 0;
#pragma unroll
            for (int a = 0; a < 8; ++a)
#pragma unroll
                for (int b = a; b < 8; ++b) {
                    acc[idx] = __builtin_amdgcn_mfma_f32_16x16x32_bf16(
                        fg[a], fg[b], acc[idx], 0, 0, 0);
                    ++idx;
                }
        }
    }

    // ---- finalize s: combine the two row-phases (lanes l and l^32)
    sacc0 += __shfl_xor(sacc0, 32);
    sacc1 += __shfl_xor(sacc1, 32);
    sacc2 += __shfl_xor(sacc2, 32);
    sacc3 += __shfl_xor(sacc3, 32);

    // ---- block reduction: 4 phases, wave ph adds its triangle (+mirror)
    __syncthreads();   // tiles region re-purposed as grid from here
    for (int ph = 0; ph < 4; ++ph) {
        if (w == ph) {
            int idx = 0;
#pragma unroll
            for (int a = 0; a < 8; ++a)
#pragma unroll
                for (int b = a; b < 8; ++b) {
#pragma unroll
                    for (int e = 0; e < 4; ++e) {
                        int row = a * 16 + (l >> 4) * 4 + e;
                        int col = b * 16 + (l & 15);
                        float val = acc[idx][e];
                        if (ph == 0) {
                            grid[row * 128 + col] = val;
                            if (a != b) grid[col * 128 + row] = val;
                        } else {
                            grid[row * 128 + col] += val;
                            if (a != b) grid[col * 128 + row] += val;
                        }
                    }
                    ++idx;
                }
            if (l < 32) {
                if (ph == 0) {
                    sgrid[4 * l + 0] = sacc0; sgrid[4 * l + 1] = sacc1;
                    sgrid[4 * l + 2] = sacc2; sgrid[4 * l + 3] = sacc3;
                } else {
                    sgrid[4 * l + 0] += sacc0; sgrid[4 * l + 1] += sacc1;
                    sgrid[4 * l + 2] += sacc2; sgrid[4 * l + 3] += sacc3;
                }
            }
        }
        __syncthreads();
    }

    // ---- dump one partial per block
    long pbase = (long)blockIdx.x * PART_STRIDE;
    for (int i = t; i < 16384; i += 256) ws[pbase + i] = grid[i];
    if (t < 128) ws[pbase + 16384 + t] = sgrid[t];
}

// ------------------------------------------------------- reduce partials -> G, s
__global__ __launch_bounds__(256) void k_reduce(const float* __restrict__ parts,
                                                float* __restrict__ g_out,
                                                float* __restrict__ s_out, int nb1) {
    __shared__ float red[256];
    int b = blockIdx.x, t = threadIdx.x;
    if (b < 512) {
        int d1 = b >> 2, q = b & 3;
        int c32 = t & 31, pg = t >> 5;
        int per = nb1 >> 3;
        int e = d1 * 128 + q * 32 + c32;
        float acc = 0.f;
#pragma unroll 4
        for (int p = pg * per; p < (pg + 1) * per; ++p)
            acc += parts[(long)p * PART_STRIDE + e];
        red[t] = acc;
        __syncthreads();
        if (pg == 0) {
            float s = red[c32];
#pragma unroll
            for (int k = 1; k < 8; ++k) s += red[k * 32 + c32];
            g_out[e] = s;
        }
    } else {
        int ee = t & 127, hg = t >> 7;
        int per = nb1 >> 1;
        float acc = 0.f;
#pragma unroll 4
        for (int p = hg * per; p < (hg + 1) * per; ++p)
            acc += parts[(long)p * PART_STRIDE + 16384 + ee];
        red[t] = acc;
        __syncthreads();
        if (hg == 0) s_out[ee] = red[ee] + red[128 + ee];
    }
}

// ---- k_mid: scores row a from G (in LDS) + softmax + M row + c/wsum + casts
__global__ __launch_bounds__(256) void k_mid(const float* __restrict__ G,
                                             const float* __restrict__ s,
                                             const float* __restrict__ Wq,
                                             const float* __restrict__ bq,
                                             const float* __restrict__ Wk,
                                             const float* __restrict__ bk,
                                             const float* __restrict__ Wv,
                                             const float* __restrict__ bv,
                                             const float* __restrict__ Wo,
                                             unsigned short* __restrict__ M16,
                                             unsigned short* __restrict__ Wo16,
                                             float* __restrict__ cvec,
                                             float* __restrict__ wsum, float Bn) {
    __shared__ float gl[16384];      // G row-major
    __shared__ float wk[128 * 129];  // Wk padded (conflict-free row reads)
    __shared__ float wqr[128], sl[128], bkl[128], bvl[128];
    __shared__ float prt[2][128], prt2[2][128];
    __shared__ float tmp[128], scl[128], wrow[128], scl2[128];
    int t = threadIdx.x, a = blockIdx.x;
    int tt = t & 127, seg = t >> 7;

    {
        const fvec4* gg = (const fvec4*)G;
        fvec4* gs = (fvec4*)gl;
        for (int i = t; i < 4096; i += 256) gs[i] = gg[i];
    }
    for (int idx = t; idx < 16384; idx += 256) {
        int r = idx >> 7, cc = idx & 127;
        wk[r * 129 + cc] = Wk[idx];
    }
    if (t < 128) {
        wqr[t] = Wq[a * 128 + t];
        sl[t] = s[t]; bkl[t] = bk[t]; bvl[t] = bv[t];
    }
    __syncthreads();

    float tm = 0.f;
#pragma unroll 8
    for (int d1 = seg * 64; d1 < seg * 64 + 64; ++d1) tm += wqr[d1] * gl[d1 * 128 + tt];
    prt[seg][tt] = tm;
    __syncthreads();
    if (t < 128) tmp[t] = prt[0][t] + prt[1][t];
    __syncthreads();

    float p1 = 0.f, p2 = 0.f;
#pragma unroll 8
    for (int d = seg * 64; d < seg * 64 + 64; ++d) {
        float w2 = wk[tt * 129 + d];
        p1 += tmp[d] * w2;
        p2 += sl[d] * w2;
    }
    prt[seg][tt] = p1;
    prt2[seg][tt] = p2;
    __syncthreads();
    if (t < 128) {
        float tdot = prt[0][t] + prt[1][t];
        float kdot = prt2[0][t] + prt2[1][t];
        float qs = 0.f;
#pragma unroll 8
        for (int d = 0; d < 128; ++d) qs += wqr[d] * sl[d];
        float bqa = bq[a];
        float sc = (tdot + qs * bkl[t] + bqa * kdot + Bn * bqa * bkl[t]) *
                   0.0883883476483184406f;
        scl[t] = sc;
    }
    __syncthreads();
    if (t < 128) {
        float mx = -1e30f;
        for (int i2 = 0; i2 < 128; ++i2) mx = fmaxf(mx, scl[i2]);
        scl2[t] = expf(scl[t] - mx);
    }
    __syncthreads();
    if (t < 128) {
        float sum = 0.f;
        for (int i2 = 0; i2 < 128; ++i2) sum += scl2[i2];
        wrow[t] = scl2[t] / sum;
    }
    __syncthreads();

    float pm = 0.f;
#pragma unroll 8
    for (int cc = seg * 64; cc < seg * 64 + 64; ++cc)
        pm += wrow[cc] * Wv[cc * 128 + tt];
    prt[seg][tt] = pm;
    __syncthreads();
    if (t < 128) {
        M16[a * 128 + t] = f2bf(prt[0][t] + prt[1][t]);
        float wo = Wo[a * 128 + t];
        Wo16[a * 128 + t] = f2bf(wo);
        scl[t] = wrow[t] * bvl[t];
        scl2[t] = wo;
    }
    __syncthreads();
    if (t < 64) { scl[t] += scl[t + 64]; scl2[t] += scl2[t + 64]; }
    __syncthreads();
    if (t == 0) {
        float cv = 0.f, wsm = 0.f;
        for (int cc = 0; cc < 64; ++cc) { cv += scl[cc]; wsm += scl2[cc]; }
        cvec[a] = cv; wsum[a] = wsm;
    }
}

// ---------------- pass 2 (bf16 input): per-group double GEMM -> output rows
__global__ __launch_bounds__(256, 2) void k_out16(const unsigned short* __restrict__ x16,
                                                  const unsigned short* __restrict__ M16,
                                                  const unsigned short* __restrict__ Wo16,
                                                  const float* __restrict__ cvec,
                                                  const float* __restrict__ wsum,
                                                  const float* __restrict__ bo,
                                                  float* __restrict__ out, int ngrp) {
    __shared__ short xsk[16384];  // X_p bf16 (XOR-swizzled); reused as U^T
    __shared__ float csl[128], wsl[128], bol[128];
    int t = threadIdx.x;
    int l = t & 63, w = t >> 6, hi = l >> 4, c = l & 15;
    int p = blockIdx.x;

    const s16x8* xg = (const s16x8*)(x16 + (size_t)p * 16384);
    s16x8 stg[8];
#pragma unroll
    for (int kk = 0; kk < 8; ++kk) stg[kk] = xg[kk * 256 + t];

    s16x8 bfM[2][4];
#pragma unroll
    for (int rt = 0; rt < 2; ++rt) {
        int r = (2 * w + rt) * 16 + c;
#pragma unroll
        for (int ks = 0; ks < 4; ++ks)
            bfM[rt][ks] = *(const s16x8*)&M16[r * 128 + ks * 32 + hi * 8];
    }
    if (t < 128) { csl[t] = cvec[t]; wsl[t] = wsum[t]; bol[t] = bo[t]; }

#pragma unroll
    for (int kk = 0; kk < 8; ++kk) {
        int ft = kk * 256 + t;
        int j = ft >> 4, d08 = (ft & 15) * 8;
        *(s16x8*)&xsk[j * 128 + (d08 ^ ((j & 7) << 3))] = stg[kk];
    }
    __syncthreads();

    f32x4 acc[8][2] = {};
#pragma unroll
    for (int jt = 0; jt < 8; ++jt) {
        int j = jt * 16 + c;
        s16x8 af[4];
#pragma unroll
        for (int ks = 0; ks < 4; ++ks)
            af[ks] = *(const s16x8*)&xsk[j * 128 + ((ks * 32 + hi * 8) ^ ((j & 7) << 3))];
#pragma unroll
        for (int rt = 0; rt < 2; ++rt)
#pragma unroll
            for (int ks = 0; ks < 4; ++ks)
                acc[jt][rt] = __builtin_amdgcn_mfma_f32_16x16x32_bf16(af[ks], bfM[rt][ks], acc[jt][rt], 0, 0, 0);
    }
    __syncthreads();

#pragma unroll
    for (int jt = 0; jt < 8; ++jt)
#pragma unroll
        for (int rt = 0; rt < 2; ++rt) {
            int r = (2 * w + rt) * 16 + c;
            int j0 = jt * 16 + hi * 4;
            uint64_t pk = 0;
#pragma unroll
            for (int e = 0; e < 4; ++e) pk |= (uint64_t)f2bf(acc[jt][rt][e]) << (16 * e);
            *(uint64_t*)&xsk[r * 128 + (j0 ^ ((r & 7) << 3))] = pk;
        }
    __syncthreads();

    s16x8 bfO[2][4];
#pragma unroll
    for (int ot = 0; ot < 2; ++ot) {
        int o = (2 * w + ot) * 16 + c;
#pragma unroll
        for (int ks = 0; ks < 4; ++ks)
            bfO[ot][ks] = *(const s16x8*)&Wo16[o * 128 + ks * 32 + hi * 8];
    }

    f32x4 acc2[8][2] = {};
#pragma unroll
    for (int rt8 = 0; rt8 < 8; ++rt8) {
        int rr = rt8 * 16 + c;
        s16x8 af[4];
#pragma unroll
        for (int ks = 0; ks < 4; ++ks)
            af[ks] = *(const s16x8*)&xsk[rr * 128 + ((ks * 32 + hi * 8) ^ ((rr & 7) << 3))];
#pragma unroll
        for (int ot = 0; ot < 2; ++ot)
#pragma unroll
            for (int ks = 0; ks < 4; ++ks)
                acc2[rt8][ot] = __builtin_amdgcn_mfma_f32_16x16x32_bf16(af[ks], bfO[ot][ks], acc2[rt8][ot], 0, 0, 0);
    }

#pragma unroll
    for (int rt8 = 0; rt8 < 8; ++rt8)
#pragma unroll
        for (int ot = 0; ot < 2; ++ot)
#pragma unroll
            for (int e = 0; e < 4; ++e) {
                int r = rt8 * 16 + hi * 4 + e;
                int o = (2 * w + ot) * 16 + c;
                float val = acc2[rt8][ot][e] + csl[r] * wsl[o] + bol[o];
                out[((long)r * ngrp + p) * 128 + o] = val;
            }
}

// ---------------- pass 2 (f32 fallback) if workspace too small — r3-style
__global__ __launch_bounds__(256) void k_out32(const float* __restrict__ x,
                                               const unsigned short* __restrict__ M16,
                                               const unsigned short* __restrict__ Wo16,
                                               const float* __restrict__ cvec,
                                               const float* __restrict__ wsum,
                                               const float* __restrict__ bo,
                                               float* __restrict__ out, int ngrp) {
    __shared__ short xsk[16384];
    __shared__ float csl[128], wsl[128], bol[128];
    int t = threadIdx.x;
    int l = t & 63, w = t >> 6, hi = l >> 4, c = l & 15;
    int p = blockIdx.x;

    s16x8 bfM[2][4];
#pragma unroll
    for (int rt = 0; rt < 2; ++rt) {
        int r = (2 * w + rt) * 16 + c;
#pragma unroll
        for (int ks = 0; ks < 4; ++ks)
            bfM[rt][ks] = *(const s16x8*)&M16[r * 128 + ks * 32 + hi * 8];
    }
    if (t < 128) { csl[t] = cvec[t]; wsl[t] = wsum[t]; bol[t] = bo[t]; }

    const fvec4* xg = (const fvec4*)x;
    long xbase = (long)p * 4096;
#pragma unroll 4
    for (int kk = 0; kk < 16; ++kk) {
        int ft = kk * 256 + t;
        fvec4 v = xg[xbase + ft];
        int j = ft >> 5, d0 = (ft & 31) * 4;
        uint64_t pk = 0;
#pragma unroll
        for (int e = 0; e < 4; ++e) pk |= (uint64_t)f2bf(v[e]) << (16 * e);
        *(uint64_t*)&xsk[j * 128 + (d0 ^ ((j & 7) << 3))] = pk;
    }
    __syncthreads();

    f32x4 acc[8][2] = {};
#pragma unroll
    for (int jt = 0; jt < 8; ++jt) {
        int j = jt * 16 + c;
        s16x8 af[4];
#pragma unroll
        for (int ks = 0; ks < 4; ++ks)
            af[ks] = *(const s16x8*)&xsk[j * 128 + ((ks * 32 + hi * 8) ^ ((j & 7) << 3))];
#pragma unroll
        for (int rt = 0; rt < 2; ++rt)
#pragma unroll
            for (int ks = 0; ks < 4; ++ks)
                acc[jt][rt] = __builtin_amdgcn_mfma_f32_16x16x32_bf16(af[ks], bfM[rt][ks], acc[jt][rt], 0, 0, 0);
    }
    __syncthreads();

#pragma unroll
    for (int jt = 0; jt < 8; ++jt)
#pragma unroll
        for (int rt = 0; rt < 2; ++rt) {
            int r = (2 * w + rt) * 16 + c;
            int j0 = jt * 16 + hi * 4;
            uint64_t pk = 0;
#pragma unroll
            for (int e = 0; e < 4; ++e) pk |= (uint64_t)f2bf(acc[jt][rt][e]) << (16 * e);
            *(uint64_t*)&xsk[r * 128 + (j0 ^ ((r & 7) << 3))] = pk;
        }
    __syncthreads();

    s16x8 bfO[2][4];
#pragma unroll
    for (int ot = 0; ot < 2; ++ot) {
        int o = (2 * w + ot) * 16 + c;
#pragma unroll
        for (int ks = 0; ks < 4; ++ks)
            bfO[ot][ks] = *(const s16x8*)&Wo16[o * 128 + ks * 32 + hi * 8];
    }

    f32x4 acc2[8][2] = {};
#pragma unroll
    for (int rt8 = 0; rt8 < 8; ++rt8) {
        int rr = rt8 * 16 + c;
        s16x8 af[4];
#pragma unroll
        for (int ks = 0; ks < 4; ++ks)
            af[ks] = *(const s16x8*)&xsk[rr * 128 + ((ks * 32 + hi * 8) ^ ((rr & 7) << 3))];
#pragma unroll
        for (int ot = 0; ot < 2; ++ot)
#pragma unroll
            for (int ks = 0; ks < 4; ++ks)
                acc2[rt8][ot] = __builtin_amdgcn_mfma_f32_16x16x32_bf16(af[ks], bfO[ot][ks], acc2[rt8][ot], 0, 0, 0);
    }

#pragma unroll
    for (int rt8 = 0; rt8 < 8; ++rt8)
#pragma unroll
        for (int ot = 0; ot < 2; ++ot)
#pragma unroll
            for (int e = 0; e < 4; ++e) {
                int r = rt8 * 16 + hi * 4 + e;
                int o = (2 * w + ot) * 16 + c;
                float val = acc2[rt8][ot][e] + csl[r] * wsl[o] + bol[o];
                out[((long)r * ngrp + p) * 128 + o] = val;
            }
}

// ------------------------------------------------------------------- launcher
extern "C" void kernel_launch(void* const* d_in, const int* in_sizes, int n_in,
                              void* d_out, int out_size, void* d_ws, size_t ws_size,
                              hipStream_t stream) {
    const float* x  = (const float*)d_in[0];
    const float* Wq = (const float*)d_in[1];
    const float* bq = (const float*)d_in[2];
    const float* Wk = (const float*)d_in[3];
    const float* bk = (const float*)d_in[4];
    const float* Wv = (const float*)d_in[5];
    const float* bv = (const float*)d_in[6];
    const float* Wo = (const float*)d_in[7];
    const float* bo = (const float*)d_in[8];
    float* out = (float*)d_out;
    float* ws = (float*)d_ws;

    int Bn  = in_sizes[0] / DD;      // 262144
    int nb1 = Bn / ROWS_PER_BLK;     // 512
    int ngrp = Bn / DD;              // 2048

    float* parts = ws;
    float* G     = ws + (size_t)nb1 * PART_STRIDE;
    float* svec  = G + 16384;
    float* cvec  = svec + 128;
    float* wsumv = cvec + 128;
    unsigned short* M16  = (unsigned short*)(wsumv + 128);
    unsigned short* Wo16 = M16 + 16384;
    unsigned short* x16  = Wo16 + 16384;
    size_t needed = (size_t)((char*)(x16 + (size_t)Bn * DD) - (char*)ws);
    bool use16 = ws_size >= needed;

    hipLaunchKernelGGL(k_gram, dim3(nb1), dim3(256), 0, stream,
                       x, ws, use16 ? x16 : (unsigned short*)nullptr);
    hipLaunchKernelGGL(k_reduce, dim3(513), dim3(256), 0, stream,
                       ws, G, svec, nb1);
    hipLaunchKernelGGL(k_mid, dim3(128), dim3(256), 0, stream,
                       G, svec, Wq, bq, Wk, bk, Wv, bv, Wo,
                       M16, Wo16, cvec, wsumv, (float)Bn);
    if (use16)
        hipLaunchKernelGGL(k_out16, dim3(ngrp), dim3(256), 0, stream,
                           x16, M16, Wo16, cvec, wsumv, bo, out, ngrp);
    else
        hipLaunchKernelGGL(k_out32, dim3(ngrp), dim3(256), 0, stream,
                           x, M16, Wo16, cvec, wsumv, bo, out, ngrp);
}